// Round 5
// baseline (378.275 us; speedup 1.0000x reference)
//
#include <hip/hip_runtime.h>
#include <hip/hip_bf16.h>
#include <math.h>

#define N 8192
#define FIN 256
#define D 64
#define ALPHA 0.2f
#define CS 2048            // columns per wave (4 waves cover N)
#define HBYTES 8192        // half-tile: 16 rows x 512 B (4 iters of 32 cols)

typedef __attribute__((ext_vector_type(8))) short bf16x8;
typedef __attribute__((ext_vector_type(4))) float f32x4;

// ---------------- Kernel 1: h = x@trans (fp32), e1/e2 (fp32), hF fragment-order
__global__ __launch_bounds__(256) void k_h_e(
    const float* __restrict__ x, const float* __restrict__ trans,
    const float* __restrict__ attn,
    __hip_bfloat16* __restrict__ hF, float* __restrict__ e1, float* __restrict__ e2)
{
    __shared__ float xs[8 * FIN];
    __shared__ __hip_bfloat16 hl[8 * D];
    const int t = threadIdx.x;
    const int r0 = blockIdx.x * 8;

    #pragma unroll
    for (int v = 0; v < 2; ++v) {
        int idx = t + 256 * v;
        ((float4*)xs)[idx] = ((const float4*)(x + (size_t)r0 * FIN))[idx];
    }
    __syncthreads();

    const int lane = t & 63, w = t >> 6;
    const float* xa = xs + (2 * w) * FIN;
    const float* xb = xs + (2 * w + 1) * FIN;
    float acca = 0.f, accb = 0.f;
    #pragma unroll 8
    for (int k = 0; k < FIN; ++k) {
        const float tv = trans[k * D + lane];
        acca = fmaf(xa[k], tv, acca);
        accb = fmaf(xb[k], tv, accb);
    }
    const int ra = r0 + 2 * w, rb = ra + 1;

    const float a1 = attn[lane], a2 = attn[D + lane];
    float p1a = acca * a1, p2a = acca * a2;
    float p1b = accb * a1, p2b = accb * a2;
    #pragma unroll
    for (int mm = 1; mm <= 32; mm <<= 1) {
        p1a += __shfl_xor(p1a, mm);
        p2a += __shfl_xor(p2a, mm);
        p1b += __shfl_xor(p1b, mm);
        p2b += __shfl_xor(p2b, mm);
    }
    if (lane == 0) { e1[ra] = p1a; e2[ra] = p2a; e1[rb] = p1b; e2[rb] = p2b; }

    hl[(2 * w) * D + lane]     = __float2bfloat16(acca);
    hl[(2 * w + 1) * D + lane] = __float2bfloat16(accb);
    __syncthreads();
    if (t < D) {
        const int q = t >> 4, m = t & 15;
        const int cb = r0 >> 5, jgrp = (r0 >> 3) & 3;
        union { bf16x8 v; __hip_bfloat16 h[8]; } o;
        #pragma unroll
        for (int r = 0; r < 8; ++r) o.h[r] = hl[r * D + q * 16 + m];
        *(bf16x8*)(hF + (((size_t)cb * 4 + q) * 64 + jgrp * 16 + m) * 8) = o.v;
    }
}

// stage one half-tile: 16 rows x 512 B.  8 DMA instrs; instr i stages rows
// 2i,2i+1 (lane L: row 2i+(L>>5), bytes (L&31)*16).  LDS dest contiguous 1 KB.
__device__ __forceinline__ void stage_half(const char* gs, char* ld) {
    #pragma unroll
    for (int i = 0; i < 8; ++i) {
        __builtin_amdgcn_global_load_lds(
            (const __attribute__((address_space(1))) void*)(gs + (size_t)i * (2u * N * 4u)),
            (__attribute__((address_space(3))) void*)(ld + i * 1024),
            16, 0, 2 /* nt */);
    }
}

// ---------------- Kernel 2: fully-fused masked softmax-attention ---------------
// Block owns 16 rows x ALL 8192 cols; wave w covers cols [2048w, 2048w+2048).
// R15: same double-buffered DMA staging as R14 but hF/e2 register prefetch at
// DISTANCE 2 (sets A/B).  vmcnt retires in issue order, so R14's distance-1
// prefetch (issued AFTER stage(h+1)) forced stage(h+1)'s HBM DMAs to retire
// ~250 cyc after issue -> ~600 cyc stall/body.  With distance 2, the prefs
// consumed by ITER0/1 of body h predate stage(h+1) in the queue; the first
// pref issued after it is consumed at ITER2 (~800 cyc later).  Queue math:
// ops younger than stage(h) at body top = 6+6+8 = 20 -> vmcnt(20) retires
// exactly stage(h); tail body uses vmcnt(12).  Numerics identical op order
// (lsum, MFMA accum, w=0..3 combine) -> bit-identical output.
__global__ __launch_bounds__(256) void k_attn(
    const int* __restrict__ mask, const __hip_bfloat16* __restrict__ hF,
    const float* __restrict__ e1, const float* __restrict__ e2,
    float* __restrict__ out)
{
    __shared__ __align__(16) char smem[4 * 2 * HBYTES];   // 64 KB (2 halves/wave)
    __shared__ float lw[4][16];
    const int t = threadIdx.x;
    const int lane = t & 63, wave = t >> 6;
    const int i0 = blockIdx.x * 16;
    const int c0 = wave * CS;
    const int m = lane & 15, quad = lane >> 4;
    const float er = e1[i0 + m];

    char* sw = smem + wave * (2 * HBYTES);
    // per-lane DMA source base: row i0+(lane>>5), col c0+(lane&31)*4
    const char* gdma = (const char*)(mask + (size_t)(i0 + (lane >> 5)) * N
                                          + c0 + (lane & 31) * 4);
    const int moff = m * 512 + quad * 32;   // reader offset within a half buffer

    const __hip_bfloat16* hfp = hF + (((size_t)(c0 >> 5)) * 4 * 64 + lane) * 8;
    const float* ep = e2 + c0 + quad * 8;

    f32x4 acc0 = {0.f, 0.f, 0.f, 0.f};
    f32x4 acc1 = {0.f, 0.f, 0.f, 0.f};
    f32x4 acc2 = {0.f, 0.f, 0.f, 0.f};
    f32x4 acc3 = {0.f, 0.f, 0.f, 0.f};
    float lsum = 0.f;

    // prologue DMA: halves 0,1 in flight (16 DMAs, oldest in queue)
    stage_half(gdma,        sw + lane * 16);
    stage_half(gdma + 512,  sw + HBYTES + lane * 16);

    // distance-2 hF/e2 prefetch: set A holds pref for even ITN, B for odd
    bf16x8 pA0 = *(const bf16x8*)(hfp);
    bf16x8 pA1 = *(const bf16x8*)(hfp + 512);
    bf16x8 pA2 = *(const bf16x8*)(hfp + 1024);
    bf16x8 pA3 = *(const bf16x8*)(hfp + 1536);
    float4 peaA = *(const float4*)(ep);
    float4 pebA = *(const float4*)(ep + 4);
    bf16x8 pB0 = *(const bf16x8*)(hfp + 2048);
    bf16x8 pB1 = *(const bf16x8*)(hfp + 2048 + 512);
    bf16x8 pB2 = *(const bf16x8*)(hfp + 2048 + 1024);
    bf16x8 pB3 = *(const bf16x8*)(hfp + 2048 + 1536);
    float4 peaB = *(const float4*)(ep + 32);
    float4 pebB = *(const float4*)(ep + 36);

#define ITER(S, P, ITN)                                                        \
    {                                                                          \
        const int4 mm0 = *(const int4*)(sb + moff + (P) * 128);                \
        const int4 mm1 = *(const int4*)(sb + moff + (P) * 128 + 16);           \
        const bf16x8 b0 = p##S##0, b1 = p##S##1, b2 = p##S##2, b3 = p##S##3;   \
        const float4 ea = pea##S, eb = peb##S;                                 \
        if ((ITN) + 2 <= 63) {   /* refill this set for ITER ITN+2 */          \
            const size_t ito = (size_t)((ITN) + 2) * 2048;                     \
            p##S##0 = *(const bf16x8*)(hfp + ito);                             \
            p##S##1 = *(const bf16x8*)(hfp + ito + 512);                       \
            p##S##2 = *(const bf16x8*)(hfp + ito + 1024);                      \
            p##S##3 = *(const bf16x8*)(hfp + ito + 1536);                      \
            pea##S = *(const float4*)(ep + ((ITN) + 2) * 32);                  \
            peb##S = *(const float4*)(ep + ((ITN) + 2) * 32 + 4);              \
        }                                                                      \
        float s0 = er + ea.x; s0 = s0 > 0.f ? s0 : ALPHA * s0;                 \
        float s1 = er + ea.y; s1 = s1 > 0.f ? s1 : ALPHA * s1;                 \
        float s2 = er + ea.z; s2 = s2 > 0.f ? s2 : ALPHA * s2;                 \
        float s3 = er + ea.w; s3 = s3 > 0.f ? s3 : ALPHA * s3;                 \
        float s4 = er + eb.x; s4 = s4 > 0.f ? s4 : ALPHA * s4;                 \
        float s5 = er + eb.y; s5 = s5 > 0.f ? s5 : ALPHA * s5;                 \
        float s6 = er + eb.z; s6 = s6 > 0.f ? s6 : ALPHA * s6;                 \
        float s7 = er + eb.w; s7 = s7 > 0.f ? s7 : ALPHA * s7;                 \
        const float p0 = mm0.x ? __expf(s0) : 0.f;                             \
        const float p1 = mm0.y ? __expf(s1) : 0.f;                             \
        const float p2 = mm0.z ? __expf(s2) : 0.f;                             \
        const float p3 = mm0.w ? __expf(s3) : 0.f;                             \
        const float p4 = mm1.x ? __expf(s4) : 0.f;                             \
        const float p5 = mm1.y ? __expf(s5) : 0.f;                             \
        const float p6 = mm1.z ? __expf(s6) : 0.f;                             \
        const float p7 = mm1.w ? __expf(s7) : 0.f;                             \
        union { bf16x8 v; __hip_bfloat162 h2[4]; } af;                         \
        af.h2[0] = __float22bfloat162_rn(make_float2(p0, p1));                 \
        af.h2[1] = __float22bfloat162_rn(make_float2(p2, p3));                 \
        af.h2[2] = __float22bfloat162_rn(make_float2(p4, p5));                 \
        af.h2[3] = __float22bfloat162_rn(make_float2(p6, p7));                 \
        lsum += ((p0 + p1) + (p2 + p3)) + ((p4 + p5) + (p6 + p7));             \
        acc0 = __builtin_amdgcn_mfma_f32_16x16x32_bf16(af.v, b0, acc0, 0, 0, 0); \
        acc1 = __builtin_amdgcn_mfma_f32_16x16x32_bf16(af.v, b1, acc1, 0, 0, 0); \
        acc2 = __builtin_amdgcn_mfma_f32_16x16x32_bf16(af.v, b2, acc2, 0, 0, 0); \
        acc3 = __builtin_amdgcn_mfma_f32_16x16x32_bf16(af.v, b3, acc3, 0, 0, 0); \
    }

    for (int h = 0; h < 15; ++h) {
        // exactly 20 VMEM ops are younger than stage(h)'s last DMA here
        // (pref_{4h} 6 + pref_{4h+1} 6 + stage(h+1) 8) -> vmcnt(20) retires
        // precisely half h's DMAs; half h+1's stay in flight.
        __builtin_amdgcn_s_waitcnt(0x4F74);   // vmcnt(20)
        __builtin_amdgcn_sched_barrier(0);
        const char* sb = sw + (h & 1) * HBYTES;
        const int itb = h * 4;
        ITER(A, 0, itb + 0)
        ITER(B, 1, itb + 1)
        ITER(A, 2, itb + 2)
        ITER(B, 3, itb + 3)
        if (h < 14) {
            // pin all pref issues ABOVE the stage so consuming them never
            // forces the new DMAs (keeps the distance-2 decoupling).
            __builtin_amdgcn_sched_barrier(0);
            stage_half(gdma + (size_t)(h + 2) * 512,
                       sw + (h & 1) * HBYTES + lane * 16);
        }
    }
    {   // tail: half 15.  Younger-than-stage(15): pref_60 6 + pref_61 6 = 12.
        __builtin_amdgcn_s_waitcnt(0x0F7C);   // vmcnt(12)
        __builtin_amdgcn_sched_barrier(0);
        const char* sb = sw + HBYTES;
        ITER(A, 0, 60)
        ITER(B, 1, 61)
        ITER(A, 2, 62)
        ITER(B, 3, 63)
    }
#undef ITER

    // per-wave row sums: row m's columns live in lanes m, m+16, m+32, m+48
    lsum += __shfl_xor(lsum, 16);
    lsum += __shfl_xor(lsum, 32);
    if (quad == 0) lw[wave][m] = lsum;

    // ---- cross-wave combine in LDS (alias over dead mask buffers) ----
    __syncthreads();   // all DMAs retired (vmcnt waits above); buffers dead
    float* cw = (float*)smem;   // [wave][row][col] = [4][16][64] fp32, 16 KB
    #pragma unroll
    for (int reg = 0; reg < 4; ++reg) {
        float* rbase = cw + (wave * 16 + quad * 4 + reg) * 64;
        rbase[m     ] = acc0[reg];
        rbase[m + 16] = acc1[reg];
        rbase[m + 32] = acc2[reg];
        rbase[m + 48] = acc3[reg];
    }
    __syncthreads();
    #pragma unroll
    for (int rr = 0; rr < 4; ++rr) {
        const int idx = rr * 256 + t;          // 0..1023
        const int r = idx >> 6, c = idx & 63;
        // sum order w=0..3 == baseline -> identical numerics
        float s = ((cw[(0 * 16 + r) * 64 + c] + cw[(1 * 16 + r) * 64 + c])
                +   cw[(2 * 16 + r) * 64 + c]) + cw[(3 * 16 + r) * 64 + c];
        float l = ((lw[0][r] + lw[1][r]) + lw[2][r]) + lw[3][r];
        out[(size_t)(i0 + r) * D + c] = s / l;
    }
}

extern "C" void kernel_launch(void* const* d_in, const int* in_sizes, int n_in,
                              void* d_out, int out_size, void* d_ws, size_t ws_size,
                              hipStream_t stream) {
    const float* x     = (const float*)d_in[0];
    const int*   mask  = (const int*)d_in[1];
    const float* trans = (const float*)d_in[2];
    const float* attn  = (const float*)d_in[3];
    float* out = (float*)d_out;

    char* ws = (char*)d_ws;
    __hip_bfloat16* hF = (__hip_bfloat16*)ws;                 // 1 MB
    char* p = ws + (size_t)D * N * sizeof(__hip_bfloat16);
    float* e1 = (float*)p;            p += (size_t)N * sizeof(float);
    float* e2 = (float*)p;            p += (size_t)N * sizeof(float);

    k_h_e<<<N / 8, 256, 0, stream>>>(x, trans, attn, hF, e1, e2);
    k_attn<<<N / 16, 256, 0, stream>>>(mask, hF, e1, e2, out);
}